// Round 1
// baseline (121.485 us; speedup 1.0000x reference)
//
#include <hip/hip_runtime.h>
#include <math.h>

// Problem constants (match reference)
#define Bdim 8
#define Lq   256
#define Hd   128
#define NHd  4
#define Dh   32

static constexpr float kNEG = -4294967295.0f;           // -(2^32)+1 as f32
static constexpr float kScale = 0.17677669529663687f;   // 1/sqrt(32)

// ---------------------------------------------------------------------------
// Normalize the bool time_mask whose device encoding is ambiguous (u8 vs i32).
// If it's u8 (np.bool_), ~10% of 2048 bytes are 1 at arbitrary offsets, so
// some nonzero byte exists at an index i%4!=0. If it's i32 (0/1 LE), nonzero
// bytes only occur at i%4==0. Reading the first n bytes is safe either way.
// ---------------------------------------------------------------------------
__global__ void normalize_mask_kernel(const unsigned char* __restrict__ raw,
                                      int* __restrict__ outmask, int n) {
    __shared__ int cnt;
    if (threadIdx.x == 0) cnt = 0;
    __syncthreads();
    for (int i = threadIdx.x; i < n; i += blockDim.x)
        if ((i & 3) && raw[i]) atomicAdd(&cnt, 1);
    __syncthreads();
    const bool is_u8 = (cnt > 0);
    const int* raw32 = (const int*)raw;
    for (int i = threadIdx.x; i < n; i += blockDim.x) {
        int v = is_u8 ? (int)raw[i] : raw32[i];
        outmask[i] = (v != 0) ? 1 : 0;
    }
}

// ---------------------------------------------------------------------------
// Projections, fused with abs_pos adds:
//   Q    = queries @ Wq^T + bq
//   Keff = keys    @ Wk^T + bk + abs_pos_K
//   Veff = keys    @ Wv^T + bv + abs_pos_V
// Block = 128 threads (one per output channel o), R=8 rows per block.
// ---------------------------------------------------------------------------
__global__ __launch_bounds__(128) void proj_kernel(
    const float* __restrict__ queries, const float* __restrict__ keys,
    const float* __restrict__ absK,    const float* __restrict__ absV,
    const float* __restrict__ Wq, const float* __restrict__ bq,
    const float* __restrict__ Wk, const float* __restrict__ bk,
    const float* __restrict__ Wv, const float* __restrict__ bv,
    float* __restrict__ Qb, float* __restrict__ Kb, float* __restrict__ Vb)
{
    constexpr int R = 8;
    __shared__ float qrows[R][Hd];
    __shared__ float krows[R][Hd];
    const int o = threadIdx.x;
    const int row0 = blockIdx.x * R;

    for (int r = 0; r < R; ++r) {
        qrows[r][o] = queries[(row0 + r) * Hd + o];
        krows[r][o] = keys[(row0 + r) * Hd + o];
    }
    __syncthreads();

    float qa[R], ka[R], va[R];
    const float bqv = bq[o], bkv = bk[o], bvv = bv[o];
    for (int r = 0; r < R; ++r) {
        qa[r] = bqv;
        ka[r] = bkv + absK[(row0 + r) * Hd + o];
        va[r] = bvv + absV[(row0 + r) * Hd + o];
    }
    for (int i = 0; i < Hd; ++i) {
        const float wq = Wq[o * Hd + i];
        const float wk = Wk[o * Hd + i];
        const float wv = Wv[o * Hd + i];
        #pragma unroll
        for (int r = 0; r < R; ++r) {
            qa[r] += qrows[r][i] * wq;
            ka[r] += krows[r][i] * wk;
            va[r] += krows[r][i] * wv;
        }
    }
    for (int r = 0; r < R; ++r) {
        Qb[(row0 + r) * Hd + o] = qa[r];
        Kb[(row0 + r) * Hd + o] = ka[r];
        Vb[(row0 + r) * Hd + o] = va[r];
    }
}

// ---------------------------------------------------------------------------
// Fused attention, one block per (b, l) query row, 256 threads = 4 waves.
// Thread map: c4 = tid&31 (float4 channel group, 128 channels), m_off = tid>>5.
// A full wave reads a contiguous 1KB (two m-rows x 512B) -> perfectly coalesced.
// Causal: m>l never needed for scores (always masked). Output needs m>l only
// for fully-masked rows (uniform 1/256 attention).
// ---------------------------------------------------------------------------
__global__ __launch_bounds__(256) void attn_kernel(
    const float* __restrict__ Qb, const float* __restrict__ Kb,
    const float* __restrict__ Vb,
    const float* __restrict__ tK, const float* __restrict__ tV,
    const int* __restrict__ tmask, float* __restrict__ out)
{
    const int b = blockIdx.x >> 8;
    const int l = blockIdx.x & 255;
    const int tid = threadIdx.x;
    const int c4 = tid & 31;      // which float4 of the 128 channels
    const int m_off = tid >> 5;   // 0..7
    const int h = c4 >> 3;        // head = channel/32

    __shared__ float qrow[Hd];
    __shared__ float sc[NHd][Lq];
    __shared__ float op[8][Hd];

    if (tid < Hd) qrow[tid] = Qb[((size_t)b * Lq + l) * Hd + tid];
    // init all scores to NEG (covers m>l and masked rows)
    for (int m = tid; m < NHd * Lq; m += 256) ((float*)sc)[m] = kNEG;
    __syncthreads();

    const bool rowmask = (tmask[b * Lq + l] != 0);
    const float4 q4 = *(const float4*)&qrow[c4 * 4];

    const float4* Kp  = (const float4*)(Kb + (size_t)b * Lq * Hd);
    const float4* tKp = (const float4*)(tK + ((size_t)(b * Lq + l)) * Lq * Hd);

    // ---- scores: s[h][m] = (Q . (Keff[m] + tK[l,m])) * scale, m <= l ----
    for (int mb = 0; mb <= l; mb += 8) {
        const int m = mb + m_off;
        if (m <= l) {
            const float4 k4 = Kp[m * 32 + c4];
            const float4 t4 = tKp[m * 32 + c4];
            float p = q4.x * (k4.x + t4.x) + q4.y * (k4.y + t4.y)
                    + q4.z * (k4.z + t4.z) + q4.w * (k4.w + t4.w);
            p += __shfl_xor(p, 1);
            p += __shfl_xor(p, 2);
            p += __shfl_xor(p, 4);
            if ((c4 & 7) == 0) {
                sc[h][m] = rowmask ? kNEG : (p * kScale);
            }
        }
    }
    __syncthreads();

    // ---- softmax: wave w handles head w ----
    {
        const int w = tid >> 6, lane = tid & 63;
        float v[4];
        float mx = -3.4e38f;
        #pragma unroll
        for (int k = 0; k < 4; ++k) {
            v[k] = sc[w][lane + 64 * k];
            mx = fmaxf(mx, v[k]);
        }
        #pragma unroll
        for (int d = 1; d < 64; d <<= 1) mx = fmaxf(mx, __shfl_xor(mx, d));
        float ssum = 0.f;
        #pragma unroll
        for (int k = 0; k < 4; ++k) {
            v[k] = expf(v[k] - mx);   // masked: exp(-4.3e9) -> 0; all-masked: exp(0)=1
            ssum += v[k];
        }
        #pragma unroll
        for (int d = 1; d < 64; d <<= 1) ssum += __shfl_xor(ssum, d);
        const float inv = 1.0f / ssum;
        #pragma unroll
        for (int k = 0; k < 4; ++k) sc[w][lane + 64 * k] = v[k] * inv;
    }
    __syncthreads();

    // ---- output: out[c] = sum_m A[h][m] * (Veff[m,c] + tV[l,m,c]) ----
    const int mlim = rowmask ? (Lq - 1) : l;
    float4 acc = {0.f, 0.f, 0.f, 0.f};
    const float4* Vp  = (const float4*)(Vb + (size_t)b * Lq * Hd);
    const float4* tVp = (const float4*)(tV + ((size_t)(b * Lq + l)) * Lq * Hd);
    for (int mb = 0; mb <= mlim; mb += 8) {
        const int m = mb + m_off;
        if (m <= mlim) {
            const float a = sc[h][m];
            const float4 v4 = Vp[m * 32 + c4];
            const float4 t4 = tVp[m * 32 + c4];
            acc.x += a * (v4.x + t4.x);
            acc.y += a * (v4.y + t4.y);
            acc.z += a * (v4.z + t4.z);
            acc.w += a * (v4.w + t4.w);
        }
    }
    ((float4*)op)[m_off * 32 + c4] = acc;
    __syncthreads();

    if (tid < Hd) {
        float s = 0.f;
        #pragma unroll
        for (int r = 0; r < 8; ++r) s += op[r][tid];
        out[((size_t)b * Lq + l) * Hd + tid] = s;
    }
}

// ---------------------------------------------------------------------------
extern "C" void kernel_launch(void* const* d_in, const int* in_sizes, int n_in,
                              void* d_out, int out_size, void* d_ws, size_t ws_size,
                              hipStream_t stream) {
    const float* queries = (const float*)d_in[0];
    const float* keys    = (const float*)d_in[1];
    const float* tK      = (const float*)d_in[2];
    const float* tV      = (const float*)d_in[3];
    const float* absK    = (const float*)d_in[4];
    const float* absV    = (const float*)d_in[5];
    const float* Wq      = (const float*)d_in[6];
    const float* bq      = (const float*)d_in[7];
    const float* Wk      = (const float*)d_in[8];
    const float* bk      = (const float*)d_in[9];
    const float* Wv      = (const float*)d_in[10];
    const float* bv      = (const float*)d_in[11];
    const unsigned char* tmask_raw = (const unsigned char*)d_in[12];
    // d_in[13] (attn_mask) is deterministic triu(k=1) -> computed in-kernel.

    float* outp = (float*)d_out;

    const int rows = Bdim * Lq;           // 2048
    float* Qb = (float*)d_ws;             // rows*Hd floats = 1 MB
    float* Kb = Qb + (size_t)rows * Hd;   // 1 MB
    float* Vb = Kb + (size_t)rows * Hd;   // 1 MB
    int* tmask = (int*)(Vb + (size_t)rows * Hd);  // 8 KB

    normalize_mask_kernel<<<1, 256, 0, stream>>>(tmask_raw, tmask, rows);
    proj_kernel<<<rows / 8, 128, 0, stream>>>(queries, keys, absK, absV,
                                              Wq, bq, Wk, bk, Wv, bv,
                                              Qb, Kb, Vb);
    attn_kernel<<<rows, 256, 0, stream>>>(Qb, Kb, Vb, tK, tV, tmask, outp);
}

// Round 2
// 106.049 us; speedup vs baseline: 1.1456x; 1.1456x over previous
//
#include <hip/hip_runtime.h>
#include <math.h>

// Problem constants (match reference)
#define Bdim 8
#define Lq   256
#define Hd   128
#define NHd  4

static constexpr float kNEG = -4294967295.0f;           // -(2^32)+1 as f32
static constexpr float kScale = 0.17677669529663687f;   // 1/sqrt(32)

// ---------------------------------------------------------------------------
// prep: blocks 0-11 transpose Wq/Wk/Wv (64x64 LDS tiles, coalesced both ways);
//       block 12 normalizes the bool time_mask (u8 vs i32 auto-detect).
// ---------------------------------------------------------------------------
__global__ __launch_bounds__(256) void prep_kernel(
    const float* __restrict__ Wq, const float* __restrict__ Wk,
    const float* __restrict__ Wv, const unsigned char* __restrict__ raw,
    float* __restrict__ Wt, int* __restrict__ outmask)
{
    const int blk = blockIdx.x;
    if (blk < 12) {
        __shared__ float tile[64][65];
        const int mi = blk >> 2;
        const float* W = (mi == 0) ? Wq : (mi == 1) ? Wk : Wv;
        float* WT = Wt + mi * (Hd * Hd);
        const int ti = blk & 3;
        const int r0 = (ti >> 1) * 64, c0 = (ti & 1) * 64;
        #pragma unroll
        for (int k = 0; k < 16; ++k) {
            const int e = threadIdx.x + k * 256;
            const int r = e >> 6, c = e & 63;
            tile[r][c] = W[(r0 + r) * Hd + (c0 + c)];
        }
        __syncthreads();
        #pragma unroll
        for (int k = 0; k < 16; ++k) {
            const int e = threadIdx.x + k * 256;
            const int r = e >> 6, c = e & 63;
            WT[(c0 + r) * Hd + (r0 + c)] = tile[c][r];
        }
    } else {
        __shared__ int cnt;
        if (threadIdx.x == 0) cnt = 0;
        __syncthreads();
        const int n = Bdim * Lq;
        for (int i = threadIdx.x; i < n; i += 256)
            if ((i & 3) && raw[i]) atomicAdd(&cnt, 1);
        __syncthreads();
        const bool is_u8 = (cnt > 0);
        const int* raw32 = (const int*)raw;
        for (int i = threadIdx.x; i < n; i += 256) {
            const int v = is_u8 ? (int)raw[i] : raw32[i];
            outmask[i] = (v != 0) ? 1 : 0;
        }
    }
}

// ---------------------------------------------------------------------------
// Projections (fused abs_pos adds), W pre-transposed so loads are coalesced:
//   Q    = queries @ Wq^T + bq
//   Keff = keys    @ Wk^T + bk + abs_pos_K
//   Veff = keys    @ Wv^T + bv + abs_pos_V
// Block = 256 threads; o = tid&127 (output channel), rh = tid>>7 (row half);
// each thread computes 4 rows. x rows staged in LDS (broadcast reads).
// ---------------------------------------------------------------------------
__global__ __launch_bounds__(256) void proj_kernel(
    const float* __restrict__ queries, const float* __restrict__ keys,
    const float* __restrict__ absK, const float* __restrict__ absV,
    const float* __restrict__ Wt,
    const float* __restrict__ bq, const float* __restrict__ bk,
    const float* __restrict__ bv,
    float* __restrict__ Qb, float* __restrict__ Kb, float* __restrict__ Vb)
{
    constexpr int R = 8;
    __shared__ float xq[R][Hd];
    __shared__ float xk[R][Hd];
    const int row0 = blockIdx.x * R;
    const int tid = threadIdx.x;
    #pragma unroll
    for (int k = 0; k < 4; ++k) {
        const int e = tid + k * 256;
        const int r = e >> 7, c = e & 127;
        xq[r][c] = queries[(row0 + r) * Hd + c];
        xk[r][c] = keys[(row0 + r) * Hd + c];
    }
    __syncthreads();

    const int o = tid & 127, rh = tid >> 7;
    const float* __restrict__ Wtq = Wt;
    const float* __restrict__ Wtk = Wt + Hd * Hd;
    const float* __restrict__ Wtv = Wt + 2 * Hd * Hd;

    float qa[4], ka[4], va[4];
    #pragma unroll
    for (int j = 0; j < 4; ++j) {
        const int r = row0 + rh * 4 + j;
        qa[j] = bq[o];
        ka[j] = bk[o] + absK[r * Hd + o];
        va[j] = bv[o] + absV[r * Hd + o];
    }
    #pragma unroll 4
    for (int i = 0; i < Hd; ++i) {
        const float wq = Wtq[i * Hd + o];
        const float wk = Wtk[i * Hd + o];
        const float wv = Wtv[i * Hd + o];
        #pragma unroll
        for (int j = 0; j < 4; ++j) {
            const float xqv = xq[rh * 4 + j][i];
            const float xkv = xk[rh * 4 + j][i];
            qa[j] += xqv * wq;
            ka[j] += xkv * wk;
            va[j] += xkv * wv;
        }
    }
    #pragma unroll
    for (int j = 0; j < 4; ++j) {
        const int r = row0 + rh * 4 + j;
        Qb[r * Hd + o] = qa[j];
        Kb[r * Hd + o] = ka[j];
        Vb[r * Hd + o] = va[j];
    }
}

// ---------------------------------------------------------------------------
// Fused attention, one block per (b, l), 256 threads = 4 waves.
// Thread map: c8 = tid&15 (8-float channel group), m_off = tid>>4 (16 m rows
// per tile). A wave reads 4 consecutive m-rows = 2 KB contiguous, 32 B/lane.
// Loads are never predicated (always in-bounds within the (b,l) slab);
// sc[h][m] is 0 for m>l after softmax so ragged tails cost only a few KB.
// ---------------------------------------------------------------------------
#define SCP 264   // padded score stride: bank = (8h + m) % 32 -> conflict-free

__global__ __launch_bounds__(256) void attn_kernel(
    const float* __restrict__ Qb, const float* __restrict__ Kb,
    const float* __restrict__ Vb,
    const float* __restrict__ tK, const float* __restrict__ tV,
    const int* __restrict__ tmask, float* __restrict__ out)
{
    const int b = blockIdx.x >> 8;
    const int l = blockIdx.x & 255;
    const int tid = threadIdx.x;
    const int c8 = tid & 15;      // which 8-float channel group
    const int m_off = tid >> 4;   // 0..15
    const int h = c8 >> 2;        // head

    __shared__ float qrow[Hd];
    __shared__ float sc[NHd][SCP];
    __shared__ float op[16][Hd];

    if (tid < Hd) qrow[tid] = Qb[((size_t)b * Lq + l) * Hd + tid];
    for (int m = tid; m < NHd * Lq; m += 256) sc[m >> 8][m & 255] = kNEG;
    __syncthreads();

    const bool rowmask = (tmask[b * Lq + l] != 0);
    const float4 q0 = *(const float4*)&qrow[c8 * 8];
    const float4 q1 = *(const float4*)&qrow[c8 * 8 + 4];

    const float4* __restrict__ Kp  = (const float4*)(Kb + (size_t)b * Lq * Hd);
    const float4* __restrict__ tKp = (const float4*)(tK + ((size_t)(b * Lq + l)) * Lq * Hd);

    // ---- scores: sc[h][m] = (Q . (Keff[m] + tK[l,m])) * scale, m <= l ----
    if (!rowmask) {
        #pragma unroll 2
        for (int mb = 0; mb <= l; mb += 16) {
            const int m = mb + m_off;
            const int base = m * 32 + c8 * 2;
            const float4 k0 = Kp[base],     k1 = Kp[base + 1];
            const float4 t0 = tKp[base],    t1 = tKp[base + 1];
            float p = q0.x * (k0.x + t0.x) + q0.y * (k0.y + t0.y)
                    + q0.z * (k0.z + t0.z) + q0.w * (k0.w + t0.w)
                    + q1.x * (k1.x + t1.x) + q1.y * (k1.y + t1.y)
                    + q1.z * (k1.z + t1.z) + q1.w * (k1.w + t1.w);
            p += __shfl_xor(p, 1);
            p += __shfl_xor(p, 2);
            if ((c8 & 3) == 0 && m <= l) sc[h][m] = p * kScale;
        }
    }
    __syncthreads();

    // ---- softmax: wave w handles head w ----
    {
        const int w = tid >> 6, lane = tid & 63;
        float v[4];
        float mx = -3.4e38f;
        #pragma unroll
        for (int k = 0; k < 4; ++k) {
            v[k] = sc[w][lane + 64 * k];
            mx = fmaxf(mx, v[k]);
        }
        #pragma unroll
        for (int d = 1; d < 64; d <<= 1) mx = fmaxf(mx, __shfl_xor(mx, d));
        float ssum = 0.f;
        #pragma unroll
        for (int k = 0; k < 4; ++k) {
            v[k] = expf(v[k] - mx);   // masked: -> 0; all-masked row: exp(0)=1
            ssum += v[k];
        }
        #pragma unroll
        for (int d = 1; d < 64; d <<= 1) ssum += __shfl_xor(ssum, d);
        const float inv = 1.0f / ssum;
        #pragma unroll
        for (int k = 0; k < 4; ++k) sc[w][lane + 64 * k] = v[k] * inv;
    }
    __syncthreads();

    // ---- output: out[c] = sum_m A[h][m] * (Veff[m,c] + tV[l,m,c]) ----
    const int mlim = rowmask ? (Lq - 1) : l;
    float4 a0 = {0.f, 0.f, 0.f, 0.f}, a1 = {0.f, 0.f, 0.f, 0.f};
    const float4* __restrict__ Vp  = (const float4*)(Vb + (size_t)b * Lq * Hd);
    const float4* __restrict__ tVp = (const float4*)(tV + ((size_t)(b * Lq + l)) * Lq * Hd);
    #pragma unroll 2
    for (int mb = 0; mb <= mlim; mb += 16) {
        const int m = mb + m_off;
        const float a = sc[h][m];           // 0 beyond l -> tail is free
        const int base = m * 32 + c8 * 2;
        const float4 v0 = Vp[base],  v1 = Vp[base + 1];
        const float4 t0 = tVp[base], t1 = tVp[base + 1];
        a0.x += a * (v0.x + t0.x); a0.y += a * (v0.y + t0.y);
        a0.z += a * (v0.z + t0.z); a0.w += a * (v0.w + t0.w);
        a1.x += a * (v1.x + t1.x); a1.y += a * (v1.y + t1.y);
        a1.z += a * (v1.z + t1.z); a1.w += a * (v1.w + t1.w);
    }
    ((float4*)&op[m_off][0])[c8 * 2]     = a0;
    ((float4*)&op[m_off][0])[c8 * 2 + 1] = a1;
    __syncthreads();

    if (tid < Hd) {
        float s = 0.f;
        #pragma unroll
        for (int r = 0; r < 16; ++r) s += op[r][tid];
        out[((size_t)b * Lq + l) * Hd + tid] = s;
    }
}

// ---------------------------------------------------------------------------
extern "C" void kernel_launch(void* const* d_in, const int* in_sizes, int n_in,
                              void* d_out, int out_size, void* d_ws, size_t ws_size,
                              hipStream_t stream) {
    const float* queries = (const float*)d_in[0];
    const float* keys    = (const float*)d_in[1];
    const float* tK      = (const float*)d_in[2];
    const float* tV      = (const float*)d_in[3];
    const float* absK    = (const float*)d_in[4];
    const float* absV    = (const float*)d_in[5];
    const float* Wq      = (const float*)d_in[6];
    const float* bq      = (const float*)d_in[7];
    const float* Wk      = (const float*)d_in[8];
    const float* bk      = (const float*)d_in[9];
    const float* Wv      = (const float*)d_in[10];
    const float* bv      = (const float*)d_in[11];
    const unsigned char* tmask_raw = (const unsigned char*)d_in[12];
    // d_in[13] (attn_mask) is deterministic triu(k=1) -> handled in-kernel.

    float* outp = (float*)d_out;

    const int rows = Bdim * Lq;                    // 2048
    float* Qb = (float*)d_ws;                      // 1 MB
    float* Kb = Qb + (size_t)rows * Hd;            // 1 MB
    float* Vb = Kb + (size_t)rows * Hd;            // 1 MB
    int* tmask = (int*)(Vb + (size_t)rows * Hd);   // 8 KB
    float* Wt = (float*)(tmask + rows);            // 192 KB (3 transposed W)

    prep_kernel<<<13, 256, 0, stream>>>(Wq, Wk, Wv, tmask_raw, Wt, tmask);
    proj_kernel<<<rows / 8, 256, 0, stream>>>(queries, keys, absK, absV, Wt,
                                              bq, bk, bv, Qb, Kb, Vb);
    attn_kernel<<<rows, 256, 0, stream>>>(Qb, Kb, Vb, tK, tV, tmask, outp);
}

// Round 4
// 99.065 us; speedup vs baseline: 1.2263x; 1.0705x over previous
//
#include <hip/hip_runtime.h>
#include <math.h>

// Problem constants (match reference)
#define Bdim 8
#define Lq   256
#define Hd   128
#define NHd  4

static constexpr float kNEG = -4294967295.0f;           // -(2^32)+1 as f32
static constexpr float kScale = 0.17677669529663687f;   // 1/sqrt(32)

// ---------------------------------------------------------------------------
// prep: blocks 0-11 transpose Wq/Wk/Wv (64x64 LDS tiles, coalesced both ways);
//       block 12 normalizes the bool time_mask (u8 vs i32 auto-detect).
// ---------------------------------------------------------------------------
__global__ __launch_bounds__(256) void prep_kernel(
    const float* __restrict__ Wq, const float* __restrict__ Wk,
    const float* __restrict__ Wv, const unsigned char* __restrict__ raw,
    float* __restrict__ Wt, int* __restrict__ outmask)
{
    const int blk = blockIdx.x;
    if (blk < 12) {
        __shared__ float tile[64][65];
        const int mi = blk >> 2;
        const float* W = (mi == 0) ? Wq : (mi == 1) ? Wk : Wv;
        float* WT = Wt + mi * (Hd * Hd);
        const int ti = blk & 3;
        const int r0 = (ti >> 1) * 64, c0 = (ti & 1) * 64;
        #pragma unroll
        for (int k = 0; k < 16; ++k) {
            const int e = threadIdx.x + k * 256;
            const int r = e >> 6, c = e & 63;
            tile[r][c] = W[(r0 + r) * Hd + (c0 + c)];
        }
        __syncthreads();
        #pragma unroll
        for (int k = 0; k < 16; ++k) {
            const int e = threadIdx.x + k * 256;
            const int r = e >> 6, c = e & 63;
            WT[(c0 + r) * Hd + (r0 + c)] = tile[c][r];
        }
    } else {
        __shared__ int cnt;
        if (threadIdx.x == 0) cnt = 0;
        __syncthreads();
        const int n = Bdim * Lq;
        for (int i = threadIdx.x; i < n; i += 256)
            if ((i & 3) && raw[i]) atomicAdd(&cnt, 1);
        __syncthreads();
        const bool is_u8 = (cnt > 0);
        const int* raw32 = (const int*)raw;
        for (int i = threadIdx.x; i < n; i += 256) {
            const int v = is_u8 ? (int)raw[i] : raw32[i];
            outmask[i] = (v != 0) ? 1 : 0;
        }
    }
}

// ---------------------------------------------------------------------------
// Projections (fused abs_pos adds), W pre-transposed so loads are coalesced.
// 512 threads (8 waves/block for latency hiding): o = tid&127, rh = tid>>7,
// each thread computes 2 rows of a block's 8.
// ---------------------------------------------------------------------------
__global__ __launch_bounds__(512) void proj_kernel(
    const float* __restrict__ queries, const float* __restrict__ keys,
    const float* __restrict__ absK, const float* __restrict__ absV,
    const float* __restrict__ Wt,
    const float* __restrict__ bq, const float* __restrict__ bk,
    const float* __restrict__ bv,
    float* __restrict__ Qb, float* __restrict__ Kb, float* __restrict__ Vb)
{
    constexpr int R = 8;
    __shared__ float xq[R][Hd];
    __shared__ float xk[R][Hd];
    const int row0 = blockIdx.x * R;
    const int tid = threadIdx.x;
    #pragma unroll
    for (int k = 0; k < 2; ++k) {
        const int e = tid + k * 512;
        const int r = e >> 7, c = e & 127;
        xq[r][c] = queries[(row0 + r) * Hd + c];
        xk[r][c] = keys[(row0 + r) * Hd + c];
    }
    __syncthreads();

    const int o = tid & 127, rh = tid >> 7;   // rh 0..3 -> rows rh*2, rh*2+1
    const int r0 = rh * 2, r1 = rh * 2 + 1;
    const float* __restrict__ Wtq = Wt;
    const float* __restrict__ Wtk = Wt + Hd * Hd;
    const float* __restrict__ Wtv = Wt + 2 * Hd * Hd;

    float qa0 = bq[o], qa1 = qa0;
    float ka0 = bk[o] + absK[(row0 + r0) * Hd + o];
    float ka1 = bk[o] + absK[(row0 + r1) * Hd + o];
    float va0 = bv[o] + absV[(row0 + r0) * Hd + o];
    float va1 = bv[o] + absV[(row0 + r1) * Hd + o];

    #pragma unroll 4
    for (int i = 0; i < Hd; ++i) {
        const float wq = Wtq[i * Hd + o];
        const float wk = Wtk[i * Hd + o];
        const float wv = Wtv[i * Hd + o];
        const float x0 = xq[r0][i], x1 = xq[r1][i];
        const float y0 = xk[r0][i], y1 = xk[r1][i];
        qa0 += x0 * wq; qa1 += x1 * wq;
        ka0 += y0 * wk; ka1 += y1 * wk;
        va0 += y0 * wv; va1 += y1 * wv;
    }
    Qb[(row0 + r0) * Hd + o] = qa0;  Qb[(row0 + r1) * Hd + o] = qa1;
    Kb[(row0 + r0) * Hd + o] = ka0;  Kb[(row0 + r1) * Hd + o] = ka1;
    Vb[(row0 + r0) * Hd + o] = va0;  Vb[(row0 + r1) * Hd + o] = va1;
}

// ---------------------------------------------------------------------------
// Fused attention, one block per (b,l), 256 threads = 4 waves.
// Wave w exclusively owns head w: channels [32w,32w+32), score row sc[w][*].
// Lane map: c8 = (w<<2)|(tid&3) (8-float channel group), m_off = (tid>>2)&15.
// Distance-1 register prefetch on all streams; masked rows take a uniform
// 1/256 fast path (exact: softmax of an all-NEG row) with no barriers.
// l is bit-reversed from blockIdx so long/short blocks mix across CUs.
// NOTE: sc has NO init pass -> every softmax read beyond the score loop's
// written range [0, nt*16) MUST be guarded (incl. tile 0 — round-3 bug).
// ---------------------------------------------------------------------------
__global__ __launch_bounds__(256) void attn_kernel(
    const float* __restrict__ Qb, const float* __restrict__ Kb,
    const float* __restrict__ Vb,
    const float* __restrict__ tK, const float* __restrict__ tV,
    const int* __restrict__ tmask, float* __restrict__ out)
{
    const int bid = blockIdx.x;
    int rl = bid & 255;                         // bit-reverse 8 bits
    rl = ((rl & 0x55) << 1) | ((rl >> 1) & 0x55);
    rl = ((rl & 0x33) << 2) | ((rl >> 2) & 0x33);
    rl = ((rl & 0x0F) << 4) | ((rl >> 4) & 0x0F);
    const int l = rl;
    const int b = bid >> 8;
    const int tid = threadIdx.x;
    const int w = tid >> 6;                     // wave = head
    const int lane = tid & 63;
    const int c8 = (w << 2) | (tid & 3);        // 8-float channel group
    const int m_off = (tid >> 2) & 15;

    __shared__ float sc[NHd][Lq];

    const size_t rowbase = ((size_t)b * Lq + l) * Hd;
    const float4 q0 = *(const float4*)(Qb + rowbase + c8 * 8);
    const float4 q1 = *(const float4*)(Qb + rowbase + c8 * 8 + 4);

    const float4* __restrict__ Kp  = (const float4*)(Kb + (size_t)b * Lq * Hd);
    const float4* __restrict__ Vp  = (const float4*)(Vb + (size_t)b * Lq * Hd);
    const float4* __restrict__ tKp = (const float4*)(tK + rowbase * Lq);
    const float4* __restrict__ tVp = (const float4*)(tV + rowbase * Lq);

    const bool rowmask = (tmask[b * Lq + l] != 0);
    const int nt = (l >> 4) + 1;                // score tiles (16 m-rows each)
    const int a0 = m_off * 32 + c8 * 2;

    if (!rowmask) {
        // ---- scores: sc[w][m] = (Q.(Keff[m]+tK[l,m]))*scale, tail = NEG ----
        int a = a0;
        float4 k0 = Kp[a], k1 = Kp[a + 1], t0 = tKp[a], t1 = tKp[a + 1];
        for (int i = 0; i < nt; ++i) {
            const int an = (i + 1 < nt) ? a + 512 : a;
            const float4 k0n = Kp[an],  k1n = Kp[an + 1];
            const float4 t0n = tKp[an], t1n = tKp[an + 1];
            float p = q0.x * (k0.x + t0.x) + q0.y * (k0.y + t0.y)
                    + q0.z * (k0.z + t0.z) + q0.w * (k0.w + t0.w)
                    + q1.x * (k1.x + t1.x) + q1.y * (k1.y + t1.y)
                    + q1.z * (k1.z + t1.z) + q1.w * (k1.w + t1.w);
            p += __shfl_xor(p, 1);
            p += __shfl_xor(p, 2);
            const int m = i * 16 + m_off;
            if ((tid & 3) == 0) sc[w][m] = (m <= l) ? p * kScale : kNEG;
            a = an; k0 = k0n; k1 = k1n; t0 = t0n; t1 = t1n;
        }
        __syncthreads();

        // ---- softmax, wave-local on own head; EVERY tile read guarded ----
        {
            float v0s = (lane       <= l) ? sc[w][lane]       : kNEG;
            float v1s = (lane + 64  <= l) ? sc[w][lane + 64]  : kNEG;
            float v2s = (lane + 128 <= l) ? sc[w][lane + 128] : kNEG;
            float v3s = (lane + 192 <= l) ? sc[w][lane + 192] : kNEG;
            float mx = fmaxf(fmaxf(v0s, v1s), fmaxf(v2s, v3s));
            #pragma unroll
            for (int d = 1; d < 64; d <<= 1) mx = fmaxf(mx, __shfl_xor(mx, d));
            v0s = expf(v0s - mx); v1s = expf(v1s - mx);
            v2s = expf(v2s - mx); v3s = expf(v3s - mx);
            float ssum = v0s + v1s + v2s + v3s;
            #pragma unroll
            for (int d = 1; d < 64; d <<= 1) ssum += __shfl_xor(ssum, d);
            const float inv = 1.0f / ssum;
            // writeback covers ALL 256 entries; m>l become exact 0
            sc[w][lane]       = v0s * inv;
            sc[w][lane + 64]  = v1s * inv;
            sc[w][lane + 128] = v2s * inv;
            sc[w][lane + 192] = v3s * inv;
        }
        __syncthreads();
    }

    // ---- output: out[c] = sum_m A[m] * (Veff[m,c] + tV[l,m,c]) ----
    const int nto = rowmask ? (Lq / 16) : nt;
    float4 acc0 = {0.f, 0.f, 0.f, 0.f}, acc1 = {0.f, 0.f, 0.f, 0.f};
    {
        int a = a0;
        float4 v0 = Vp[a], v1 = Vp[a + 1], t0 = tVp[a], t1 = tVp[a + 1];
        for (int i = 0; i < nto; ++i) {
            const int an = (i + 1 < nto) ? a + 512 : a;
            const float4 v0n = Vp[an],  v1n = Vp[an + 1];
            const float4 t0n = tVp[an], t1n = tVp[an + 1];
            const int m = i * 16 + m_off;
            const float aw = rowmask ? 0.00390625f : sc[w][m];
            acc0.x += aw * (v0.x + t0.x); acc0.y += aw * (v0.y + t0.y);
            acc0.z += aw * (v0.z + t0.z); acc0.w += aw * (v0.w + t0.w);
            acc1.x += aw * (v1.x + t1.x); acc1.y += aw * (v1.y + t1.y);
            acc1.z += aw * (v1.z + t1.z); acc1.w += aw * (v1.w + t1.w);
            a = an; v0 = v0n; v1 = v1n; t0 = t0n; t1 = t1n;
        }
    }
    // reduce across the 16 m_off lane-groups (bits 2..5 of lane)
    #pragma unroll
    for (int d = 4; d < 64; d <<= 1) {
        acc0.x += __shfl_xor(acc0.x, d); acc0.y += __shfl_xor(acc0.y, d);
        acc0.z += __shfl_xor(acc0.z, d); acc0.w += __shfl_xor(acc0.w, d);
        acc1.x += __shfl_xor(acc1.x, d); acc1.y += __shfl_xor(acc1.y, d);
        acc1.z += __shfl_xor(acc1.z, d); acc1.w += __shfl_xor(acc1.w, d);
    }
    if (m_off == 0) {
        *(float4*)(out + rowbase + c8 * 8)     = acc0;
        *(float4*)(out + rowbase + c8 * 8 + 4) = acc1;
    }
}

// ---------------------------------------------------------------------------
extern "C" void kernel_launch(void* const* d_in, const int* in_sizes, int n_in,
                              void* d_out, int out_size, void* d_ws, size_t ws_size,
                              hipStream_t stream) {
    const float* queries = (const float*)d_in[0];
    const float* keys    = (const float*)d_in[1];
    const float* tK      = (const float*)d_in[2];
    const float* tV      = (const float*)d_in[3];
    const float* absK    = (const float*)d_in[4];
    const float* absV    = (const float*)d_in[5];
    const float* Wq      = (const float*)d_in[6];
    const float* bq      = (const float*)d_in[7];
    const float* Wk      = (const float*)d_in[8];
    const float* bk      = (const float*)d_in[9];
    const float* Wv      = (const float*)d_in[10];
    const float* bv      = (const float*)d_in[11];
    const unsigned char* tmask_raw = (const unsigned char*)d_in[12];
    // d_in[13] (attn_mask) is deterministic triu(k=1) -> handled in-kernel.

    float* outp = (float*)d_out;

    const int rows = Bdim * Lq;                    // 2048
    float* Qb = (float*)d_ws;                      // 1 MB
    float* Kb = Qb + (size_t)rows * Hd;            // 1 MB
    float* Vb = Kb + (size_t)rows * Hd;            // 1 MB
    int* tmask = (int*)(Vb + (size_t)rows * Hd);   // 8 KB
    float* Wt = (float*)(tmask + rows);            // 192 KB (3 transposed W)

    prep_kernel<<<13, 256, 0, stream>>>(Wq, Wk, Wv, tmask_raw, Wt, tmask);
    proj_kernel<<<rows / 8, 512, 0, stream>>>(queries, keys, absK, absV, Wt,
                                              bq, bk, bv, Qb, Kb, Vb);
    attn_kernel<<<rows, 256, 0, stream>>>(Qb, Kb, Vb, tK, tV, tmask, outp);
}